// Round 15
// baseline (34.307 us; speedup 1.0000x reference)
//
#include <hip/hip_runtime.h>
#include <hip/hip_bf16.h>

// Problem constants (match reference)
#define BB 16384
#define DD 512
#define NCLS 90
#define KC 32
#define BUCKET 512   // max samples per class (mean 182, +24 sigma headroom)
#define PRB 180      // center-norm blocks in k_prep (2880 rows / 16 waves)

typedef __attribute__((ext_vector_type(8))) short short8;   // 8 bf16 (4 VGPRs)
typedef __attribute__((ext_vector_type(4))) float fx4;      // MFMA accumulator

static __device__ __forceinline__ short f2bf(float f) {
    unsigned u = __float_as_uint(f);
    unsigned r = (u + 0x7fffu + ((u >> 16) & 1u)) >> 16;    // RNE
    return (short)r;
}
// pack 8 f32 -> 8 bf16 (RNE, v_cvt_pk_bf16_f32)
static __device__ __forceinline__ short8 pack8(float4 a, float4 b) {
    union { __hip_bfloat162 h[4]; short8 s; } u;
    u.h[0] = __float22bfloat162_rn(make_float2(a.x, a.y));
    u.h[1] = __float22bfloat162_rn(make_float2(a.z, a.w));
    u.h[2] = __float22bfloat162_rn(make_float2(b.x, b.y));
    u.h[3] = __float22bfloat162_rn(make_float2(b.z, b.w));
    return u.s;
}
static __device__ __forceinline__ void gload_lds16(const void* g, void* l) {
    __builtin_amdgcn_global_load_lds(
        (const __attribute__((address_space(1))) void*)g,
        (__attribute__((address_space(3))) void*)l, 16, 0, 0);
}

// ------- K1: prep = center norm (blocks 0..179) + binning w/ dest (180..269) -
// R9-verbatim structure; binning now emits dest[sample] = bucket slot (inverse
// map) instead of idx[slot] = sample -- K3 never needs sample ids.
__global__ __launch_bounds__(1024)
void k_prep(const float* __restrict__ centers, const int* __restrict__ labels,
            short* __restrict__ cni, int* __restrict__ dest, int* __restrict__ cnt) {
    __shared__ int lab[BB];       // 64 KiB label cache for binning blocks
    __shared__ int wcnt[16];

    int t = threadIdx.x, w = t >> 6, lane = t & 63;

    if ((int)blockIdx.x < PRB) {
        int row = blockIdx.x * 16 + w;                  // 0..2879
        const float4* p = (const float4*)(centers + (size_t)row * DD);
        float4 a = p[lane * 2];
        float4 b = p[lane * 2 + 1];
        float s = a.x * a.x + a.y * a.y + a.z * a.z + a.w * a.w
                + b.x * b.x + b.y * b.y + b.z * b.z + b.w * b.w;
#pragma unroll
        for (int m = 1; m < 64; m <<= 1) s += __shfl_xor(s, m, 64);
        float sc = rsqrtf(s + 1e-12f);
        short8 v;
        v[0] = f2bf(a.x * sc); v[1] = f2bf(a.y * sc);
        v[2] = f2bf(a.z * sc); v[3] = f2bf(a.w * sc);
        v[4] = f2bf(b.x * sc); v[5] = f2bf(b.y * sc);
        v[6] = f2bf(b.z * sc); v[7] = f2bf(b.w * sc);
        *(short8*)(cni + (size_t)row * DD + lane * 8) = v;
    } else {
        int c = blockIdx.x - PRB;
        for (int j = t; j < BB / 4; j += 1024)
            ((int4*)lab)[j] = ((const int4*)labels)[j];
        __syncthreads();

        int seg4 = w * (BB / 4 / 16);
        int cw = 0;
#pragma unroll
        for (int jj = 0; jj < 4; jj++) {
            int4 v = ((int4*)lab)[seg4 + jj * 64 + lane];
            cw += (v.x == c) + (v.y == c) + (v.z == c) + (v.w == c);
        }
#pragma unroll
        for (int m = 1; m < 64; m <<= 1) cw += __shfl_xor(cw, m, 64);
        if (lane == 0) wcnt[w] = cw;
        __syncthreads();
        int pos = c * BUCKET;
        for (int ww = 0; ww < w; ww++) pos += wcnt[ww];
#pragma unroll
        for (int jj = 0; jj < 4; jj++) {
            int4 v = ((int4*)lab)[seg4 + jj * 64 + lane];
            int gbase = (seg4 + jj * 64 + lane) * 4;
            { bool m = (v.x == c); unsigned long long k = __ballot(m);
              if (m) dest[gbase]     = pos + __popcll(k & ((1ull << lane) - 1ull)); pos += __popcll(k); }
            { bool m = (v.y == c); unsigned long long k = __ballot(m);
              if (m) dest[gbase + 1] = pos + __popcll(k & ((1ull << lane) - 1ull)); pos += __popcll(k); }
            { bool m = (v.z == c); unsigned long long k = __ballot(m);
              if (m) dest[gbase + 2] = pos + __popcll(k & ((1ull << lane) - 1ull)); pos += __popcll(k); }
            { bool m = (v.w == c); unsigned long long k = __ballot(m);
              if (m) dest[gbase + 3] = pos + __popcll(k & ((1ull << lane) - 1ull)); pos += __popcll(k); }
        }
        if (t == 0) {
            int s = 0;
#pragma unroll
            for (int i = 0; i < 16; i++) s += wcnt[i];
            cnt[c] = s;
        }
    }
}

// ------- K2: stream x in natural order -> norm + bf16 + scatter to buckets ---
// One wave per row: coalesced 2KB f32 read at streaming BW; 1KB bf16 write to
// the class-bucketed image xb (lands in L3), pre-swizzled for K3's MFMA reads.
__global__ __launch_bounds__(1024)
void k_stream(const float* __restrict__ x, const int* __restrict__ dest,
              short* __restrict__ xb, float* __restrict__ xinv) {
    int row = blockIdx.x * 16 + (threadIdx.x >> 6);     // 0..16383
    int lane = threadIdx.x & 63;
    int slot = dest[row];                               // broadcast load
    const float4* p = (const float4*)(x + (size_t)row * DD);
    float4 a = p[lane * 2];
    float4 b = p[lane * 2 + 1];
    float s = a.x * a.x + a.y * a.y + a.z * a.z + a.w * a.w
            + b.x * b.x + b.y * b.y + b.z * b.z + b.w * b.w;
#pragma unroll
    for (int m = 1; m < 64; m <<= 1) s += __shfl_xor(s, m, 64);
    // lane == 16B chunk index 0..63; store at swizzled position (slot&7 key)
    *(short8*)(xb + (size_t)slot * DD + ((lane ^ (slot & 7)) << 3)) = pack8(a, b);
    if (lane == 0) xinv[slot] = rsqrtf(s + 1e-12f);
}

// ------- K3: main — contiguous DMA staging from L3-hot buckets + MFMA --------
__launch_bounds__(256, 2)
__global__ void k_main(const short* __restrict__ xb,
                       const float* __restrict__ xinv_g,
                       const short* __restrict__ cni,
                       const int* __restrict__ cnt,
                       float* __restrict__ partials) {
    __shared__ __align__(16) short c_lds[KC * DD];   // 32 KiB bf16, XOR-swizzled
    __shared__ __align__(16) short x_lds[32 * DD];   // 32 KiB bf16, XOR-swizzled
    __shared__ float S_lds[32][33];
    __shared__ float red[256];

    int c = blockIdx.x >> 3;
    int p = blockIdx.x & 7;
    int n = cnt[c];
    int nch = (n + 31) >> 5;
    int t = threadIdx.x, w = t >> 6, lane = t & 63;
    float loss_acc = 0.f;

    if (p < nch) {
        const short* cbase = cni + (size_t)c * KC * DD;
#pragma unroll
        for (int it = 0; it < 8; it++) {
            int q = t + 256 * it;                 // 16B chunk 0..2047, linear LDS
            int drow = q >> 6, cc = q & 63;
            gload_lds16(cbase + drow * DD + (cc ^ (drow & 7)) * 8, &c_lds[q * 8]);
        }

        int mrow = ((w & 1) << 4) + (lane & 15);
        int nrow = ((w >> 1) << 4) + (lane & 15);
        int row8 = t >> 3, l8 = t & 7;            // 8 threads per sample row

        for (int ch = p; ch < nch; ch += 8) {
            int off = ch << 5;
            int rem = n - off;                    // > 0

            // ---- stage 32 bucketed rows: pure DMA, fully contiguous source ----
            const short* xbase = xb + (size_t)(c * BUCKET + off) * DD;
#pragma unroll
            for (int it = 0; it < 8; it++) {
                int q = t + 256 * it;             // storage is pre-swizzled
                gload_lds16(xbase + q * 8, &x_lds[q * 8]);
            }
            float xv = xinv_g[c * BUCKET + off + row8];   // L2/L3-hot broadcast
            __syncthreads();                      // drains all gload_lds

            // ---- MFMA: S[32 samples][32 k] in 4 wave-quadrants ----
            fx4 acc = {0.f, 0.f, 0.f, 0.f};
#pragma unroll
            for (int ks = 0; ks < 16; ks++) {
                int c16a = ks * 4 + (lane >> 4);
                short8 av = *(const short8*)&x_lds[mrow * DD + ((c16a ^ (mrow & 7)) << 3)];
                short8 bv = *(const short8*)&c_lds[nrow * DD + ((c16a ^ (nrow & 7)) << 3)];
                acc = __builtin_amdgcn_mfma_f32_16x16x32_bf16(av, bv, acc, 0, 0, 0);
            }
#pragma unroll
            for (int j = 0; j < 4; j++) {
                int r = ((w & 1) << 4) + ((lane >> 4) << 2) + j;   // C/D row
                int col = ((w >> 1) << 4) + (lane & 15);           // C/D col
                S_lds[r][col] = acc[j];
            }
            __syncthreads();

            // ---- softmax over K=32 + per-sample loss; 8 threads per row ----
            {
                int q4 = l8 << 2;
                float s0 = S_lds[row8][q4 + 0] * xv;
                float s1 = S_lds[row8][q4 + 1] * xv;
                float s2 = S_lds[row8][q4 + 2] * xv;
                float s3 = S_lds[row8][q4 + 3] * xv;
                float mx = fmaxf(fmaxf(s0, s1), fmaxf(s2, s3));
#pragma unroll
                for (int m = 1; m < 8; m <<= 1) mx = fmaxf(mx, __shfl_xor(mx, m, 64));
                float e0 = expf(s0 - mx), e1 = expf(s1 - mx);
                float e2 = expf(s2 - mx), e3 = expf(s3 - mx);
                float Z = e0 + e1 + e2 + e3;
                float num = e0 * (1.f - s0) + e1 * (1.f - s1)
                          + e2 * (1.f - s2) + e3 * (1.f - s3);
#pragma unroll
                for (int m = 1; m < 8; m <<= 1) {
                    Z += __shfl_xor(Z, m, 64);
                    num += __shfl_xor(num, m, 64);
                }
                if (l8 == 0 && row8 < rem) loss_acc += num / Z;
            }
            __syncthreads();   // protect x_lds/S_lds before next chunk
        }
    }

    // ---- per-block fixed-order partial reduction ----
    red[t] = loss_acc;
    __syncthreads();
    for (int h = 128; h > 0; h >>= 1) {
        if (t < h) red[t] += red[t + h];
        __syncthreads();
    }
    if (t == 0) partials[blockIdx.x] = red[0];
}

// ------- K4: deterministic final mean over 720 block partials ----------------
__global__ void k_final(const float* __restrict__ partials, float* __restrict__ out) {
    __shared__ float red[256];
    int t = threadIdx.x;
    float s = 0.f;
    for (int i = t; i < NCLS * 8; i += 256) s += partials[i];
    red[t] = s;
    __syncthreads();
    for (int h = 128; h > 0; h >>= 1) {
        if (t < h) red[t] += red[t + h];
        __syncthreads();
    }
    if (t == 0) out[0] = red[0] * (1.0f / (float)BB);
}

extern "C" void kernel_launch(void* const* d_in, const int* in_sizes, int n_in,
                              void* d_out, int out_size, void* d_ws, size_t ws_size,
                              hipStream_t stream) {
    const float* x       = (const float*)d_in[0];
    const int*   labels  = (const int*)d_in[1];
    const float* centers = (const float*)d_in[2];
    float* out = (float*)d_out;

    char* ws = (char*)d_ws;                                  // 256 MiB workspace
    short* cni      = (short*)(ws + 0);                      //  2.95 MB
    short* xb       = (short*)(ws + (4u << 20));             // 47.2 MB bucketed bf16 x
    float* xinv     = (float*)(ws + (56u << 20));            //  184 KB
    int*   dest     = (int*)(ws + (57u << 20));              //   64 KB
    int*   cnt      = (int*)(ws + (58u << 20));              //  360 B
    float* partials = (float*)(ws + (58u << 20) + 4096);     //  2.9 KB

    k_prep<<<PRB + NCLS, 1024, 0, stream>>>(centers, labels, cni, dest, cnt);
    k_stream<<<BB / 16, 1024, 0, stream>>>(x, dest, xb, xinv);
    k_main<<<NCLS * 8, 256, 0, stream>>>(xb, xinv, cni, cnt, partials);
    k_final<<<1, 256, 0, stream>>>(partials, out);
}